// Round 9
// baseline (317.972 us; speedup 1.0000x reference)
//
#include <hip/hip_runtime.h>
#include <hip/hip_bf16.h>

typedef float f32x4 __attribute__((ext_vector_type(4)));
typedef float f32x16 __attribute__((ext_vector_type(16)));
typedef short s16x8 __attribute__((ext_vector_type(8)));
typedef int i32x4 __attribute__((ext_vector_type(4)));
typedef unsigned short u16;

__constant__ float NF4_TBL[16] = {
    -1.0f, -0.6961928009986877f, -0.5250730514526367f, -0.39491748809814453f,
    -0.28444138169288635f, -0.18477343022823334f, -0.09105003625154495f, 0.0f,
    0.07958029955625534f, 0.16093020141124725f, 0.24611230194568634f,
    0.33791524171829224f, 0.44070982933044434f, 0.5626170039176941f,
    0.7229568362236023f, 1.0f};

static __device__ __forceinline__ unsigned short f2bf(float f) {
  unsigned u = __builtin_bit_cast(unsigned, f);
  u += 0x7fffu + ((u >> 16) & 1u);  // RNE
  return (unsigned short)(u >> 16);
}

static __device__ __forceinline__ void gload16(const void* g, void* l) {
  __builtin_amdgcn_global_load_lds(
      (const __attribute__((address_space(1))) unsigned*)g,
      (__attribute__((address_space(3))) unsigned*)l, 16, 0, 0);
}

// ---------------- fused prep: X fp32->bf16 and NF4 W->bf16 ----------------
__global__ __launch_bounds__(256)
void prep(const float* __restrict__ x, const int* __restrict__ codes,
          const float* __restrict__ absmax, u16* __restrict__ xb,
          u16* __restrict__ wb, long long nx, long long nk) {
  __shared__ float lut[512];
  for (int j = threadIdx.x; j < 512; j += 256) lut[j] = NF4_TBL[j >> 5];
  __syncthreads();
  long long i = ((long long)blockIdx.x * 256 + threadIdx.x) * 8;
  if (i < nx) {
    f32x4 a = *(const f32x4*)(x + i);
    f32x4 b = *(const f32x4*)(x + i + 4);
    s16x8 o;
#pragma unroll
    for (int j = 0; j < 4; ++j) {
      o[j] = (short)f2bf(a[j]);
      o[j + 4] = (short)f2bf(b[j]);
    }
    *(s16x8*)(xb + i) = o;
  } else {
    long long e = i - nx;
    if (e < nk) {
      const int ln31 = threadIdx.x & 31;
      i32x4 c0 = *(const i32x4*)(codes + e);
      i32x4 c1 = *(const i32x4*)(codes + e + 4);
      float am = absmax[e >> 6];
      s16x8 o;
#pragma unroll
      for (int j = 0; j < 4; ++j) {
        o[j] = (short)f2bf(lut[(c0[j] << 5) + ln31] * am);
        o[j + 4] = (short)f2bf(lut[(c1[j] << 5) + ln31] * am);
      }
      *(s16x8*)(wb + e) = o;
    }
  }
}

// standalone dequant for the mid fallback path
__global__ __launch_bounds__(256)
void dequant_w(const int* __restrict__ codes, const float* __restrict__ absmax,
               u16* __restrict__ wq, long long total) {
  __shared__ float lut[512];
  for (int j = threadIdx.x; j < 512; j += 256) lut[j] = NF4_TBL[j >> 5];
  __syncthreads();
  const int ln31 = threadIdx.x & 31;
  long long e = ((long long)blockIdx.x * 256 + threadIdx.x) * 8;
  if (e >= total) return;
  i32x4 c0 = *(const i32x4*)(codes + e);
  i32x4 c1 = *(const i32x4*)(codes + e + 4);
  float am = absmax[e >> 6];
  s16x8 o;
#pragma unroll
  for (int j = 0; j < 4; ++j) {
    o[j] = (short)f2bf(lut[(c0[j] << 5) + ln31] * am);
    o[j + 4] = (short)f2bf(lut[(c1[j] << 5) + ln31] * am);
  }
  *(s16x8*)(wq + e) = o;
}

// ===== main: 256x256 bf16 GEMM, BK=64, 32x32x16, 2-barrier/K-tile =====
// Round-9: collapse 4 phases/K-tile -> 2 barrier sections with counted lgkm.
// Per tile t (buf = t&1):
//   [entry: A0(t), B0(t) reads in flight, issued post-VM-gate of tile t-1]
//   T-barrier; read B1(t); S1-stage (A-h1 of t+1)
//   lgkm(4)  -> Q00 (A0 x B0)           // B1 drains under Q00
//   lgkm(0)  -> Q01 (A0 x B1)
//   MID-barrier                          // proves all buf reads of t retired
//   read A1(t); S2..S4 stages (t+2, same buf -- readers proven done)
//   VM6 gate                             // retires ALL of (t+1)'s stages
//   lgkm(0)  -> Q21, Q20
//   read A0(t+1), B0(t+1)                // drain across next T-barrier
// vmcnt induction: post-VM6 outstanding = newest 3 stage-ops (6 gloads) every
// tile; prologue leaves exactly t1's 3 ops in flight. Register-neutral vs R8
// (aa/bnP/bnQ single-set; cluster order closes each WAR window before reuse).
#define VM6() asm volatile("s_waitcnt vmcnt(6)" ::: "memory")
#define VM0() asm volatile("s_waitcnt vmcnt(0)" ::: "memory")
#define LGKM4() asm volatile("s_waitcnt lgkmcnt(4)" ::: "memory")
#define LGKM0() asm volatile("s_waitcnt lgkmcnt(0)" ::: "memory")
#define SB0() __builtin_amdgcn_sched_barrier(0)

// one cluster: 2 m-tiles x 4 k-steps into acc[MB..MB+1][NB]
#define MM32(AV, BV, MB, NB)                                               \
  do {                                                                     \
    __builtin_amdgcn_s_setprio(1);                                         \
    _Pragma("unroll") for (int s_ = 0; s_ < 4; ++s_)                       \
    _Pragma("unroll") for (int mp_ = 0; mp_ < 2; ++mp_)                    \
        acc[(MB) + mp_][NB] = __builtin_amdgcn_mfma_f32_32x32x16_bf16(     \
            AV[mp_][s_], BV[s_], acc[(MB) + mp_][NB], 0, 0, 0);            \
    __builtin_amdgcn_s_setprio(0);                                         \
  } while (0)

__global__ __launch_bounds__(512, 2)
void gemm32(const u16* __restrict__ A, const u16* __restrict__ B,
            const float* __restrict__ BIAS, float* __restrict__ OUT,
            int M, int N, int K) {
  __shared__ __align__(16) char lds[131072];  // 2 buf x (A 32K + B 32K)

  const int tid = threadIdx.x;
  const int lane = tid & 63;
  const int wid = tid >> 6;
  const int wr = wid >> 2;  // 0..1 : M-half (128 rows)
  const int wc = wid & 3;   // 0..3 : N-quarter (64 cols)

  int nwg = (int)gridDim.x;
  int b = (int)blockIdx.x;
  if ((nwg & 7) == 0) b = (b & 7) * (nwg >> 3) + (b >> 3);  // XCD swizzle
  const int ntm = M / 256;
  const int tn = b / ntm;  // column-major tile order: B-panel L2 reuse
  const int tm = b % ntm;

  const long long K2 = (long long)K * 2;
  // ---- staging source (pre-swizzled 16B slot within 128B K-row) ----
  const int trow = tid >> 3;
  const int skey = (trow & 7) ^ ((trow >> 3) & 3);
  const int scol = ((tid & 7) ^ skey) << 4;
  const char* sgA =
      (const char*)A + ((long long)tm * 256 + trow) * K2 + scol;
  const char* sgB = (const char*)B +
                    ((long long)tn * 256 + (tid >> 8) * 64 + (trow & 31)) * K2 +
                    scol;
  const int sldso = tid * 16;

  // stage one half-tile (2 x gload16)
  auto stA = [&](int kt, int buf, int h) {
    char* d = lds + buf * 65536 + h * 16384 + sldso;
    const char* s = sgA + (long long)h * 64 * K2 + (long long)kt * 128;
    gload16(s, d);
    gload16(s + 128 * K2, d + 8192);
  };
  auto stB = [&](int kt, int buf, int h) {
    char* d = lds + buf * 65536 + 32768 + h * 16384 + sldso;
    const char* s = sgB + (long long)h * 32 * K2 + (long long)kt * 128;
    gload16(s, d);
    gload16(s + 128 * K2, d + 8192);
  };

  // ---- fragment read addressing (32x32x16: A row=lane&31, k=(lane>>5)*8+j)
  const int l31 = lane & 31;
  const int lk = lane >> 5;
  const int rkey = (l31 & 7) ^ ((l31 >> 3) & 3);
  int aslot[4];
#pragma unroll
  for (int s_ = 0; s_ < 4; ++s_) aslot[s_] = ((s_ * 2 + lk) ^ rkey) << 4;

  s16x8 aa[2][4], bnP[4], bnQ[4];
  auto rdA32 = [&](int buf, int h) {
    const char* p = lds + buf * 65536 + h * 16384 + (wr * 64 + l31) * 128;
#pragma unroll
    for (int mp_ = 0; mp_ < 2; ++mp_)
#pragma unroll
      for (int s_ = 0; s_ < 4; ++s_)
        aa[mp_][s_] = *(const s16x8*)(p + mp_ * 4096 + aslot[s_]);
  };
  auto rdB32 = [&](int buf, int h, s16x8(&bv)[4]) {
    const char* p =
        lds + buf * 65536 + 32768 + h * 16384 + (wc * 32 + l31) * 128;
#pragma unroll
    for (int s_ = 0; s_ < 4; ++s_) bv[s_] = *(const s16x8*)(p + aslot[s_]);
  };

  f32x16 acc[4][2];
  {
    f32x16 zz;
#pragma unroll
    for (int r = 0; r < 16; ++r) zz[r] = 0.f;
#pragma unroll
    for (int m_ = 0; m_ < 4; ++m_)
#pragma unroll
      for (int n_ = 0; n_ < 2; ++n_) acc[m_][n_] = zz;
  }

  const int nkt = K / 64;
  const int nit = nkt / 2;

  // prologue: t0 complete; t1 all but A-h1 (staged by S1 of tile 0)
  stB(0, 0, 0);
  stA(0, 0, 0);
  stB(0, 0, 1);
  stA(0, 0, 1);
  stB(1, 1, 0);
  stA(1, 1, 0);
  stB(1, 1, 1);
  VM6();  // t0's 4 ops retired; t1's 3 ops may stay in flight
  __builtin_amdgcn_s_barrier();
  rdA32(0, 0);       // A0(t0) -> aa
  rdB32(0, 0, bnP);  // B0(t0)

  for (int it = 0; it < nit; ++it) {
    const int kt = 2 * it;
    const bool full = (it + 1 < nit);
    SB0();
    // ===== tile kt (buf0) =====
    __builtin_amdgcn_s_barrier();  // T
    SB0();
    rdB32(0, 1, bnQ);   // B1(kt)
    stA(kt + 1, 1, 1);  // S1: completes kt+1 (region's readers >=1 barrier ago)
    LGKM4();            // A0,B0 done (B1 = newest 4 outstanding)
    SB0();
    MM32(aa, bnP, 0, 0);  // Q00
    LGKM0();
    SB0();
    MM32(aa, bnQ, 0, 1);  // Q01
    __builtin_amdgcn_s_barrier();  // MID: all waves' buf0(kt) reads retired
    SB0();
    rdA32(0, 1);  // A1(kt) -> aa  (WAR ok: Q01 issued)
    if (full) {
      stB(kt + 2, 0, 0);  // S2..S4: kt+2 into buf0 (readers proven done)
      stA(kt + 2, 0, 0);
      stB(kt + 2, 0, 1);
      VM6();  // gate: kt+1 stages (S1 + prev-odd S2'..S4') retired
    } else {
      VM0();
    }
    LGKM0();
    SB0();
    MM32(aa, bnQ, 2, 1);  // Q21
    MM32(aa, bnP, 2, 0);  // Q20
    rdA32(1, 0);          // A0(kt+1) -> aa (post-gate; drains across barrier)
    rdB32(1, 0, bnP);     // B0(kt+1)
    // ===== tile kt+1 (buf1) =====
    __builtin_amdgcn_s_barrier();  // T
    SB0();
    rdB32(1, 1, bnQ);             // B1(kt+1)
    if (full) stA(kt + 2, 0, 1);  // S1': completes kt+2
    LGKM4();
    SB0();
    MM32(aa, bnP, 0, 0);
    LGKM0();
    SB0();
    MM32(aa, bnQ, 0, 1);
    __builtin_amdgcn_s_barrier();  // MID
    SB0();
    rdA32(1, 1);  // A1(kt+1)
    if (full) {
      stB(kt + 3, 1, 0);
      stA(kt + 3, 1, 0);
      stB(kt + 3, 1, 1);
      VM6();  // gate: kt+2 stages retired
    }
    LGKM0();
    SB0();
    MM32(aa, bnQ, 2, 1);
    MM32(aa, bnP, 2, 0);
    if (full) {
      rdA32(0, 0);       // A0(kt+2)
      rdB32(0, 0, bnP);  // B0(kt+2)
    }
  }

  // epilogue: 32x32 C/D layout col=lane&31, row=(r&3)+8*(r>>2)+4*(lane>>5)
  const int ocol = tn * 256 + wc * 64 + l31;
  const int orow0 = tm * 256 + wr * 128 + 4 * lk;
  const float bv0 = BIAS[ocol];
  const float bv1 = BIAS[ocol + 32];
#pragma unroll
  for (int m_ = 0; m_ < 4; ++m_)
#pragma unroll
    for (int n_ = 0; n_ < 2; ++n_) {
      const float bb = n_ ? bv1 : bv0;
#pragma unroll
      for (int r = 0; r < 16; ++r) {
        const int row = orow0 + m_ * 32 + (r & 3) + 8 * (r >> 2);
        OUT[(long long)row * N + ocol + n_ * 32] = acc[m_][n_][r] + bb;
      }
    }
}

// ---------------- fallback: 128x128 reg-staged kernel ----------------
#define BM 128
#define BN 128
#define BK 64

template <bool FUSED>
static __device__ __forceinline__ void stage_load(
    const float* __restrict__ ap0, const int* __restrict__ cp0,
    const u16* __restrict__ wp0, const float* __restrict__ am0, int K, int kt,
    f32x4 (&ar)[4][2], i32x4 (&cr)[4][2], s16x8 (&wreg)[4], float (&amr)[4]) {
  const size_t ko = (size_t)kt * BK;
#pragma unroll
  for (int p = 0; p < 4; ++p) {
    const float* ap = ap0 + (size_t)(p * 32) * K + ko;
    ar[p][0] = *(const f32x4*)ap;
    ar[p][1] = *(const f32x4*)(ap + 4);
    if constexpr (FUSED) {
      const int* cp = cp0 + (size_t)(p * 32) * K + ko;
      cr[p][0] = *(const i32x4*)cp;
      cr[p][1] = *(const i32x4*)(cp + 4);
      amr[p] = am0[p * 32 * (K >> 6) + kt];
    } else {
      wreg[p] = *(const s16x8*)(wp0 + (size_t)(p * 32) * K + ko);
    }
  }
}

template <bool FUSED>
__global__ __launch_bounds__(256, 2)
void gemm_nf4(const float* __restrict__ X, const int* __restrict__ CODES,
              const u16* __restrict__ WQ, const float* __restrict__ AMAX,
              const float* __restrict__ BIAS, float* __restrict__ OUT,
              int M, int N, int K) {
  __shared__ short As[BM * BK];
  __shared__ short Bs[BN * BK];
  __shared__ float lut[512];

  const int tid = threadIdx.x;
  const int lane = tid & 63;
  const int wid = tid >> 6;

  if constexpr (FUSED) {
#pragma unroll
    for (int j = 0; j < 2; ++j) {
      int idx = tid + j * 256;
      lut[idx] = NF4_TBL[idx >> 5];
    }
  }

  int nwg = (int)gridDim.x;
  int b = (int)blockIdx.x;
  if ((nwg & 7) == 0) b = (b & 7) * (nwg >> 3) + (b >> 3);
  const int ntn = N / BN;
  const int tm = b / ntn;
  const int tn = b % ntn;

  const int srow = tid >> 3;
  const int scol = (tid & 7) * 8;
  const int ln31 = tid & 31;
  const int swz_w = (srow & 7) << 4;

  const float* ap0 = X + (size_t)(tm * BM + srow) * K + scol;
  const int* cp0 = CODES + (size_t)(tn * BN + srow) * K + scol;
  const u16* wp0 = WQ + (size_t)(tn * BN + srow) * K + scol;
  const float* am0 = AMAX + (size_t)(tn * BN + srow) * (K >> 6);

  f32x4 ar[4][2];
  i32x4 cr[4][2];
  s16x8 wreg[4];
  float amr[4];

  f32x4 acc[4][4];
#pragma unroll
  for (int i = 0; i < 4; ++i)
#pragma unroll
    for (int j = 0; j < 4; ++j) {
      f32x4 z = {0.f, 0.f, 0.f, 0.f};
      acc[i][j] = z;
    }

  const int wr = wid >> 1;
  const int wc = wid & 1;
  const int frow = lane & 15;
  const int fcolb = (lane >> 4) * 16;
  const int arow = wr * 64 + frow;
  const int brow = wc * 64 + frow;
  const int aswz = (arow & 7) << 4;
  const int bswz = (brow & 7) << 4;
  const char* asp = (const char*)As + arow * 128;
  const char* bsp = (const char*)Bs + brow * 128;
  char* awp = (char*)As + srow * 128 + ((scol * 2) ^ swz_w);
  char* bwp = (char*)Bs + srow * 128 + ((scol * 2) ^ swz_w);

  const int nkt = K / BK;
  stage_load<FUSED>(ap0, cp0, wp0, am0, K, 0, ar, cr, wreg, amr);

  for (int kt = 0; kt < nkt; ++kt) {
    __syncthreads();
#pragma unroll
    for (int p = 0; p < 4; ++p) {
      s16x8 av;
#pragma unroll
      for (int j = 0; j < 4; ++j) {
        av[j] = (short)f2bf(ar[p][0][j]);
        av[j + 4] = (short)f2bf(ar[p][1][j]);
      }
      *(s16x8*)(awp + p * 32 * 128) = av;
      s16x8 bv;
      if constexpr (FUSED) {
        float am = amr[p];
#pragma unroll
        for (int j = 0; j < 4; ++j) {
          bv[j] = (short)f2bf(lut[(cr[p][0][j] << 5) + ln31] * am);
          bv[j + 4] = (short)f2bf(lut[(cr[p][1][j] << 5) + ln31] * am);
        }
      } else {
        bv = wreg[p];
      }
      *(s16x8*)(bwp + p * 32 * 128) = bv;
    }
    __syncthreads();

    if (kt + 1 < nkt)
      stage_load<FUSED>(ap0, cp0, wp0, am0, K, kt + 1, ar, cr, wreg, amr);

#pragma unroll
    for (int kk = 0; kk < 2; ++kk) {
      const int qa = (fcolb | (kk << 6)) ^ aswz;
      const int qb = (fcolb | (kk << 6)) ^ bswz;
      s16x8 afr[4], bfr[4];
#pragma unroll
      for (int mi = 0; mi < 4; ++mi)
        afr[mi] = *(const s16x8*)(asp + mi * 2048 + qa);
#pragma unroll
      for (int ni = 0; ni < 4; ++ni)
        bfr[ni] = *(const s16x8*)(bsp + ni * 2048 + qb);
#pragma unroll
      for (int mi = 0; mi < 4; ++mi)
#pragma unroll
        for (int ni = 0; ni < 4; ++ni)
          acc[mi][ni] = __builtin_amdgcn_mfma_f32_16x16x32_bf16(
              afr[mi], bfr[ni], acc[mi][ni], 0, 0, 0);
    }
  }

  const int crow = tm * BM + wr * 64 + ((lane >> 4) << 2);
  const int ccol = tn * BN + wc * 64 + frow;
  float bvv[4];
#pragma unroll
  for (int ni = 0; ni < 4; ++ni) bvv[ni] = BIAS[ccol + ni * 16];
#pragma unroll
  for (int mi = 0; mi < 4; ++mi)
#pragma unroll
    for (int ni = 0; ni < 4; ++ni) {
#pragma unroll
      for (int j = 0; j < 4; ++j) {
        OUT[(size_t)(crow + mi * 16 + j) * N + ccol + ni * 16] =
            acc[mi][ni][j] + bvv[ni];
      }
    }
}

extern "C" void kernel_launch(void* const* d_in, const int* in_sizes, int n_in,
                              void* d_out, int out_size, void* d_ws,
                              size_t ws_size, hipStream_t stream) {
  const float* x = (const float*)d_in[0];
  const int* codes = (const int*)d_in[1];
  const float* absmax = (const float*)d_in[2];
  const float* bias = (const float*)d_in[3];
  float* out = (float*)d_out;

  const int N = in_sizes[3];                    // out features
  const long long nk = (long long)in_sizes[1];  // N*K
  const int K = (int)(nk / N);
  const int M = in_sizes[0] / K;

  const size_t needA = (size_t)M * K * 2;
  const size_t needB = (size_t)N * K * 2;

  const bool big_ok = (ws_size >= needA + needB) && (M % 256 == 0) &&
                      (N % 256 == 0) && (K % 128 == 0) && (K >= 512);

  if (big_ok) {
    u16* xb = (u16*)d_ws;
    u16* wb = (u16*)((char*)d_ws + needA);
    long long nx = (long long)M * K;
    long long tot8 = (nx + nk) / 8;
    prep<<<(int)((tot8 + 255) / 256), 256, 0, stream>>>(x, codes, absmax, xb,
                                                        wb, nx, nk);
    dim3 grid((M / 256) * (N / 256)), blk(512);
    gemm32<<<grid, blk, 0, stream>>>(xb, wb, bias, out, M, N, K);
  } else if (ws_size >= needB) {
    u16* wq = (u16*)d_ws;
    dequant_w<<<(int)((nk / 8 + 255) / 256), 256, 0, stream>>>(codes, absmax,
                                                               wq, nk);
    dim3 grid((M / BM) * (N / BN)), blk(256);
    gemm_nf4<false><<<grid, blk, 0, stream>>>(x, codes, wq, absmax, bias, out,
                                              M, N, K);
  } else {
    dim3 grid((M / BM) * (N / BN)), blk(256);
    gemm_nf4<true><<<grid, blk, 0, stream>>>(x, codes, (const u16*)nullptr,
                                             absmax, bias, out, M, N, K);
  }
}

// Round 10
// 292.857 us; speedup vs baseline: 1.0858x; 1.0858x over previous
//
#include <hip/hip_runtime.h>
#include <hip/hip_bf16.h>

typedef float f32x4 __attribute__((ext_vector_type(4)));
typedef float f32x16 __attribute__((ext_vector_type(16)));
typedef short s16x8 __attribute__((ext_vector_type(8)));
typedef int i32x4 __attribute__((ext_vector_type(4)));
typedef unsigned short u16;

__constant__ float NF4_TBL[16] = {
    -1.0f, -0.6961928009986877f, -0.5250730514526367f, -0.39491748809814453f,
    -0.28444138169288635f, -0.18477343022823334f, -0.09105003625154495f, 0.0f,
    0.07958029955625534f, 0.16093020141124725f, 0.24611230194568634f,
    0.33791524171829224f, 0.44070982933044434f, 0.5626170039176941f,
    0.7229568362236023f, 1.0f};

static __device__ __forceinline__ unsigned short f2bf(float f) {
  unsigned u = __builtin_bit_cast(unsigned, f);
  u += 0x7fffu + ((u >> 16) & 1u);  // RNE
  return (unsigned short)(u >> 16);
}

static __device__ __forceinline__ void gload16(const void* g, void* l) {
  __builtin_amdgcn_global_load_lds(
      (const __attribute__((address_space(1))) unsigned*)g,
      (__attribute__((address_space(3))) unsigned*)l, 16, 0, 0);
}

// ---------------- fused prep: X fp32->bf16 and NF4 W->bf16 ----------------
__global__ __launch_bounds__(256)
void prep(const float* __restrict__ x, const int* __restrict__ codes,
          const float* __restrict__ absmax, u16* __restrict__ xb,
          u16* __restrict__ wb, long long nx, long long nk) {
  __shared__ float lut[512];
  for (int j = threadIdx.x; j < 512; j += 256) lut[j] = NF4_TBL[j >> 5];
  __syncthreads();
  long long i = ((long long)blockIdx.x * 256 + threadIdx.x) * 8;
  if (i < nx) {
    f32x4 a = *(const f32x4*)(x + i);
    f32x4 b = *(const f32x4*)(x + i + 4);
    s16x8 o;
#pragma unroll
    for (int j = 0; j < 4; ++j) {
      o[j] = (short)f2bf(a[j]);
      o[j + 4] = (short)f2bf(b[j]);
    }
    *(s16x8*)(xb + i) = o;
  } else {
    long long e = i - nx;
    if (e < nk) {
      const int ln31 = threadIdx.x & 31;
      i32x4 c0 = *(const i32x4*)(codes + e);
      i32x4 c1 = *(const i32x4*)(codes + e + 4);
      float am = absmax[e >> 6];
      s16x8 o;
#pragma unroll
      for (int j = 0; j < 4; ++j) {
        o[j] = (short)f2bf(lut[(c0[j] << 5) + ln31] * am);
        o[j + 4] = (short)f2bf(lut[(c1[j] << 5) + ln31] * am);
      }
      *(s16x8*)(wb + e) = o;
    }
  }
}

// standalone dequant for the mid fallback path
__global__ __launch_bounds__(256)
void dequant_w(const int* __restrict__ codes, const float* __restrict__ absmax,
               u16* __restrict__ wq, long long total) {
  __shared__ float lut[512];
  for (int j = threadIdx.x; j < 512; j += 256) lut[j] = NF4_TBL[j >> 5];
  __syncthreads();
  const int ln31 = threadIdx.x & 31;
  long long e = ((long long)blockIdx.x * 256 + threadIdx.x) * 8;
  if (e >= total) return;
  i32x4 c0 = *(const i32x4*)(codes + e);
  i32x4 c1 = *(const i32x4*)(codes + e + 4);
  float am = absmax[e >> 6];
  s16x8 o;
#pragma unroll
  for (int j = 0; j < 4; ++j) {
    o[j] = (short)f2bf(lut[(c0[j] << 5) + ln31] * am);
    o[j + 4] = (short)f2bf(lut[(c1[j] << 5) + ln31] * am);
  }
  *(s16x8*)(wq + e) = o;
}

// ===== main: 256x256 bf16 GEMM, BK=64, 8-phase, 32x32x16 =====
// Round-10: R8 skeleton (balanced 8/4/8/4 phases, one barrier/phase) with
// the forced per-phase lgkmcnt(0)+sched_barrier REMOVED. LDS returns are
// in-order; the compiler inserts fine-grained counted lgkmcnt(N) before each
// MFMA's first use (m97 evidence), so the read drain now pipelines INTO the
// MFMA cluster instead of fully serializing before it. A-reads issue s-major
// (= consumption order) so the first MFMA pair releases after ~2/8 reads.
// All reads retire before each phase's cluster ends (every read has a
// consumer in-cluster), which precedes the next barrier -> R8's stage-WAR
// proof carries over unchanged. vmcnt induction identical to R8.
#define VM6() asm volatile("s_waitcnt vmcnt(6)" ::: "memory")
#define VM0() asm volatile("s_waitcnt vmcnt(0)" ::: "memory")
#define BAR() __builtin_amdgcn_s_barrier()

// one phase's MFMA cluster: 2 m-tiles x 4 k-steps into acc[MB..MB+1][NB]
#define MM32(AV, BV, MB, NB)                                               \
  do {                                                                     \
    __builtin_amdgcn_s_setprio(1);                                         \
    _Pragma("unroll") for (int s_ = 0; s_ < 4; ++s_)                       \
    _Pragma("unroll") for (int mp_ = 0; mp_ < 2; ++mp_)                    \
        acc[(MB) + mp_][NB] = __builtin_amdgcn_mfma_f32_32x32x16_bf16(     \
            AV[mp_][s_], BV[s_], acc[(MB) + mp_][NB], 0, 0, 0);            \
    __builtin_amdgcn_s_setprio(0);                                         \
  } while (0)

__global__ __launch_bounds__(512, 2)
void gemm32(const u16* __restrict__ A, const u16* __restrict__ B,
            const float* __restrict__ BIAS, float* __restrict__ OUT,
            int M, int N, int K) {
  __shared__ __align__(16) char lds[131072];  // 2 buf x (A 32K + B 32K)

  const int tid = threadIdx.x;
  const int lane = tid & 63;
  const int wid = tid >> 6;
  const int wr = wid >> 2;  // 0..1 : M-half (128 rows)
  const int wc = wid & 3;   // 0..3 : N-quarter (64 cols)

  int nwg = (int)gridDim.x;
  int b = (int)blockIdx.x;
  if ((nwg & 7) == 0) b = (b & 7) * (nwg >> 3) + (b >> 3);  // XCD swizzle
  const int ntm = M / 256;
  const int tn = b / ntm;  // column-major tile order: B-panel L2 reuse
  const int tm = b % ntm;

  const long long K2 = (long long)K * 2;
  // ---- staging source (pre-swizzled 16B slot within 128B K-row) ----
  const int trow = tid >> 3;
  const int skey = (trow & 7) ^ ((trow >> 3) & 3);
  const int scol = ((tid & 7) ^ skey) << 4;
  const char* sgA =
      (const char*)A + ((long long)tm * 256 + trow) * K2 + scol;
  const char* sgB = (const char*)B +
                    ((long long)tn * 256 + (tid >> 8) * 64 + (trow & 31)) * K2 +
                    scol;
  const int sldso = tid * 16;

  // stage one half-tile (2 x gload16)
  auto stA = [&](int kt, int buf, int h) {
    char* d = lds + buf * 65536 + h * 16384 + sldso;
    const char* s = sgA + (long long)h * 64 * K2 + (long long)kt * 128;
    gload16(s, d);
    gload16(s + 128 * K2, d + 8192);
  };
  auto stB = [&](int kt, int buf, int h) {
    char* d = lds + buf * 65536 + 32768 + h * 16384 + sldso;
    const char* s = sgB + (long long)h * 32 * K2 + (long long)kt * 128;
    gload16(s, d);
    gload16(s + 128 * K2, d + 8192);
  };

  // ---- fragment read addressing (32x32x16: A row=lane&31, k=(lane>>5)*8+j)
  const int l31 = lane & 31;
  const int lk = lane >> 5;
  const int rkey = (l31 & 7) ^ ((l31 >> 3) & 3);
  int aslot[4];
#pragma unroll
  for (int s_ = 0; s_ < 4; ++s_) aslot[s_] = ((s_ * 2 + lk) ^ rkey) << 4;

  s16x8 aa[2][4], bnP[4], bnQ[4];
  // s-major issue order == MFMA consumption order (enables counted-wait
  // pipelining of the drain into the cluster)
  auto rdA32 = [&](int buf, int h) {
    const char* p = lds + buf * 65536 + h * 16384 + (wr * 64 + l31) * 128;
#pragma unroll
    for (int s_ = 0; s_ < 4; ++s_)
#pragma unroll
      for (int mp_ = 0; mp_ < 2; ++mp_)
        aa[mp_][s_] = *(const s16x8*)(p + mp_ * 4096 + aslot[s_]);
  };
  auto rdB32 = [&](int buf, int h, s16x8(&bv)[4]) {
    const char* p =
        lds + buf * 65536 + 32768 + h * 16384 + (wc * 32 + l31) * 128;
#pragma unroll
    for (int s_ = 0; s_ < 4; ++s_) bv[s_] = *(const s16x8*)(p + aslot[s_]);
  };

  f32x16 acc[4][2];
  {
    f32x16 zz;
#pragma unroll
    for (int r = 0; r < 16; ++r) zz[r] = 0.f;
#pragma unroll
    for (int m_ = 0; m_ < 4; ++m_)
#pragma unroll
      for (int n_ = 0; n_ < 2; ++n_) acc[m_][n_] = zz;
  }

  const int nkt = K / 64;
  const int nit = nkt / 2;

  // prologue: buf0 <- kt0 (full), buf1 <- kt1 (all but A-half-1)
  stB(0, 0, 0);
  stA(0, 0, 0);
  stB(0, 0, 1);
  stA(0, 0, 1);
  stB(1, 1, 0);
  stA(1, 1, 0);
  stB(1, 1, 1);
  VM6();  // buf0 complete; buf1's newest 3 stages may stay in flight
  BAR();
  rdB32(0, 0, bnP);  // pre-read B0 of kt0

  for (int it = 0; it < nit; ++it) {
    const int kt = 2 * it;
    const bool full = (it + 1 < nit);
    // ---- p1: Q00 = (m0-1, n0) of kt ---- reads A0 (8)
    rdA32(0, 0);
    stA(kt + 1, 1, 1);  // buf1.A-h1 <- kt+1 (read at p7)
    BAR();
    MM32(aa, bnP, 0, 0);
    // ---- p2: Q01 ---- reads B1 kt (4)
    rdB32(0, 1, bnQ);
    if (full) stB(kt + 2, 0, 0);
    BAR();
    MM32(aa, bnQ, 0, 1);
    // ---- p3: Q21 ---- reads A1 kt (8)
    rdA32(0, 1);
    if (full) stA(kt + 2, 0, 0);
    BAR();
    MM32(aa, bnQ, 2, 1);
    // ---- p4: Q20 ---- VM6 gate; reads B0 of kt+1 (post-VM6)
    if (full) {
      stB(kt + 2, 0, 1);
      VM6();
    } else {
      VM0();
    }
    rdB32(1, 0, bnQ);  // buf1-B-h0 staged p6-prev, retired by this gate
    BAR();
    MM32(aa, bnP, 2, 0);  // bnP = B0 of kt
    // ---- p5: Q00' of kt+1 ---- reads A0' (8)
    rdA32(1, 0);
    if (full) stA(kt + 2, 0, 1);
    BAR();
    MM32(aa, bnQ, 0, 0);
    // ---- p6: Q01' ---- reads B1' (4)
    rdB32(1, 1, bnP);  // bnP last used p4
    if (full) stB(kt + 3, 1, 0);
    BAR();
    MM32(aa, bnP, 0, 1);
    // ---- p7: Q21' ---- reads A1' (8)
    rdA32(1, 1);
    if (full) stA(kt + 3, 1, 0);
    BAR();
    MM32(aa, bnP, 2, 1);
    // ---- p8: Q20' ---- VM6 gate; reads B0 of kt+2 (post-VM6)
    if (full) {
      stB(kt + 3, 1, 1);
      VM6();
      rdB32(0, 0, bnP);  // buf0-B-h0 staged p2, retired by this VM6
    }
    BAR();
    MM32(aa, bnQ, 2, 0);  // bnQ = B0 of kt+1
  }

  // epilogue: 32x32 C/D layout col=lane&31, row=(r&3)+8*(r>>2)+4*(lane>>5)
  const int ocol = tn * 256 + wc * 64 + l31;
  const int orow0 = tm * 256 + wr * 128 + 4 * lk;
  const float bv0 = BIAS[ocol];
  const float bv1 = BIAS[ocol + 32];
#pragma unroll
  for (int m_ = 0; m_ < 4; ++m_)
#pragma unroll
    for (int n_ = 0; n_ < 2; ++n_) {
      const float bb = n_ ? bv1 : bv0;
#pragma unroll
      for (int r = 0; r < 16; ++r) {
        const int row = orow0 + m_ * 32 + (r & 3) + 8 * (r >> 2);
        OUT[(long long)row * N + ocol + n_ * 32] = acc[m_][n_][r] + bb;
      }
    }
}

// ---------------- fallback: 128x128 reg-staged kernel ----------------
#define BM 128
#define BN 128
#define BK 64

template <bool FUSED>
static __device__ __forceinline__ void stage_load(
    const float* __restrict__ ap0, const int* __restrict__ cp0,
    const u16* __restrict__ wp0, const float* __restrict__ am0, int K, int kt,
    f32x4 (&ar)[4][2], i32x4 (&cr)[4][2], s16x8 (&wreg)[4], float (&amr)[4]) {
  const size_t ko = (size_t)kt * BK;
#pragma unroll
  for (int p = 0; p < 4; ++p) {
    const float* ap = ap0 + (size_t)(p * 32) * K + ko;
    ar[p][0] = *(const f32x4*)ap;
    ar[p][1] = *(const f32x4*)(ap + 4);
    if constexpr (FUSED) {
      const int* cp = cp0 + (size_t)(p * 32) * K + ko;
      cr[p][0] = *(const i32x4*)cp;
      cr[p][1] = *(const i32x4*)(cp + 4);
      amr[p] = am0[p * 32 * (K >> 6) + kt];
    } else {
      wreg[p] = *(const s16x8*)(wp0 + (size_t)(p * 32) * K + ko);
    }
  }
}

template <bool FUSED>
__global__ __launch_bounds__(256, 2)
void gemm_nf4(const float* __restrict__ X, const int* __restrict__ CODES,
              const u16* __restrict__ WQ, const float* __restrict__ AMAX,
              const float* __restrict__ BIAS, float* __restrict__ OUT,
              int M, int N, int K) {
  __shared__ short As[BM * BK];
  __shared__ short Bs[BN * BK];
  __shared__ float lut[512];

  const int tid = threadIdx.x;
  const int lane = tid & 63;
  const int wid = tid >> 6;

  if constexpr (FUSED) {
#pragma unroll
    for (int j = 0; j < 2; ++j) {
      int idx = tid + j * 256;
      lut[idx] = NF4_TBL[idx >> 5];
    }
  }

  int nwg = (int)gridDim.x;
  int b = (int)blockIdx.x;
  if ((nwg & 7) == 0) b = (b & 7) * (nwg >> 3) + (b >> 3);
  const int ntn = N / BN;
  const int tm = b / ntn;
  const int tn = b % ntn;

  const int srow = tid >> 3;
  const int scol = (tid & 7) * 8;
  const int ln31 = tid & 31;
  const int swz_w = (srow & 7) << 4;

  const float* ap0 = X + (size_t)(tm * BM + srow) * K + scol;
  const int* cp0 = CODES + (size_t)(tn * BN + srow) * K + scol;
  const u16* wp0 = WQ + (size_t)(tn * BN + srow) * K + scol;
  const float* am0 = AMAX + (size_t)(tn * BN + srow) * (K >> 6);

  f32x4 ar[4][2];
  i32x4 cr[4][2];
  s16x8 wreg[4];
  float amr[4];

  f32x4 acc[4][4];
#pragma unroll
  for (int i = 0; i < 4; ++i)
#pragma unroll
    for (int j = 0; j < 4; ++j) {
      f32x4 z = {0.f, 0.f, 0.f, 0.f};
      acc[i][j] = z;
    }

  const int wr = wid >> 1;
  const int wc = wid & 1;
  const int frow = lane & 15;
  const int fcolb = (lane >> 4) * 16;
  const int arow = wr * 64 + frow;
  const int brow = wc * 64 + frow;
  const int aswz = (arow & 7) << 4;
  const int bswz = (brow & 7) << 4;
  const char* asp = (const char*)As + arow * 128;
  const char* bsp = (const char*)Bs + brow * 128;
  char* awp = (char*)As + srow * 128 + ((scol * 2) ^ swz_w);
  char* bwp = (char*)Bs + srow * 128 + ((scol * 2) ^ swz_w);

  const int nkt = K / BK;
  stage_load<FUSED>(ap0, cp0, wp0, am0, K, 0, ar, cr, wreg, amr);

  for (int kt = 0; kt < nkt; ++kt) {
    __syncthreads();
#pragma unroll
    for (int p = 0; p < 4; ++p) {
      s16x8 av;
#pragma unroll
      for (int j = 0; j < 4; ++j) {
        av[j] = (short)f2bf(ar[p][0][j]);
        av[j + 4] = (short)f2bf(ar[p][1][j]);
      }
      *(s16x8*)(awp + p * 32 * 128) = av;
      s16x8 bv;
      if constexpr (FUSED) {
        float am = amr[p];
#pragma unroll
        for (int j = 0; j < 4; ++j) {
          bv[j] = (short)f2bf(lut[(cr[p][0][j] << 5) + ln31] * am);
          bv[j + 4] = (short)f2bf(lut[(cr[p][1][j] << 5) + ln31] * am);
        }
      } else {
        bv = wreg[p];
      }
      *(s16x8*)(bwp + p * 32 * 128) = bv;
    }
    __syncthreads();

    if (kt + 1 < nkt)
      stage_load<FUSED>(ap0, cp0, wp0, am0, K, kt + 1, ar, cr, wreg, amr);

#pragma unroll
    for (int kk = 0; kk < 2; ++kk) {
      const int qa = (fcolb | (kk << 6)) ^ aswz;
      const int qb = (fcolb | (kk << 6)) ^ bswz;
      s16x8 afr[4], bfr[4];
#pragma unroll
      for (int mi = 0; mi < 4; ++mi)
        afr[mi] = *(const s16x8*)(asp + mi * 2048 + qa);
#pragma unroll
      for (int ni = 0; ni < 4; ++ni)
        bfr[ni] = *(const s16x8*)(bsp + ni * 2048 + qb);
#pragma unroll
      for (int mi = 0; mi < 4; ++mi)
#pragma unroll
        for (int ni = 0; ni < 4; ++ni)
          acc[mi][ni] = __builtin_amdgcn_mfma_f32_16x16x32_bf16(
              afr[mi], bfr[ni], acc[mi][ni], 0, 0, 0);
    }
  }

  const int crow = tm * BM + wr * 64 + ((lane >> 4) << 2);
  const int ccol = tn * BN + wc * 64 + frow;
  float bvv[4];
#pragma unroll
  for (int ni = 0; ni < 4; ++ni) bvv[ni] = BIAS[ccol + ni * 16];
#pragma unroll
  for (int mi = 0; mi < 4; ++mi)
#pragma unroll
    for (int ni = 0; ni < 4; ++ni) {
#pragma unroll
      for (int j = 0; j < 4; ++j) {
        OUT[(size_t)(crow + mi * 16 + j) * N + ccol + ni * 16] =
            acc[mi][ni][j] + bvv[ni];
      }
    }
}

extern "C" void kernel_launch(void* const* d_in, const int* in_sizes, int n_in,
                              void* d_out, int out_size, void* d_ws,
                              size_t ws_size, hipStream_t stream) {
  const float* x = (const float*)d_in[0];
  const int* codes = (const int*)d_in[1];
  const float* absmax = (const float*)d_in[2];
  const float* bias = (const float*)d_in[3];
  float* out = (float*)d_out;

  const int N = in_sizes[3];                    // out features
  const long long nk = (long long)in_sizes[1];  // N*K
  const int K = (int)(nk / N);
  const int M = in_sizes[0] / K;

  const size_t needA = (size_t)M * K * 2;
  const size_t needB = (size_t)N * K * 2;

  const bool big_ok = (ws_size >= needA + needB) && (M % 256 == 0) &&
                      (N % 256 == 0) && (K % 128 == 0) && (K >= 512);

  if (big_ok) {
    u16* xb = (u16*)d_ws;
    u16* wb = (u16*)((char*)d_ws + needA);
    long long nx = (long long)M * K;
    long long tot8 = (nx + nk) / 8;
    prep<<<(int)((tot8 + 255) / 256), 256, 0, stream>>>(x, codes, absmax, xb,
                                                        wb, nx, nk);
    dim3 grid((M / 256) * (N / 256)), blk(512);
    gemm32<<<grid, blk, 0, stream>>>(xb, wb, bias, out, M, N, K);
  } else if (ws_size >= needB) {
    u16* wq = (u16*)d_ws;
    dequant_w<<<(int)((nk / 8 + 255) / 256), 256, 0, stream>>>(codes, absmax,
                                                               wq, nk);
    dim3 grid((M / BM) * (N / BN)), blk(256);
    gemm_nf4<false><<<grid, blk, 0, stream>>>(x, codes, wq, absmax, bias, out,
                                              M, N, K);
  } else {
    dim3 grid((M / BM) * (N / BN)), blk(256);
    gemm_nf4<true><<<grid, blk, 0, stream>>>(x, codes, (const u16*)nullptr,
                                             absmax, bias, out, M, N, K);
  }
}